// Round 19
// baseline (288.201 us; speedup 1.0000x reference)
//
#include <hip/hip_runtime.h>
#include <math.h>

#ifndef M_PI
#define M_PI 3.14159265358979323846
#endif

typedef short bf16x8 __attribute__((ext_vector_type(8)));
typedef _Float16 f16x8 __attribute__((ext_vector_type(8)));
typedef float f32x4 __attribute__((ext_vector_type(4)));

union FragU { uint4 u; bf16x8 f; };
union F16U { uint4 u; f16x8 f; _Float16 h[8]; };

typedef const __attribute__((address_space(1))) void GVoid;
typedef __attribute__((address_space(3))) void LVoid;

// round-to-nearest-even bf16, returned as bits in HIGH 16 (low 16 zero)
__device__ __forceinline__ unsigned rn_hi(float x) {
    unsigned u = __float_as_uint(x);
    unsigned r = u + 0x7FFFu + ((u >> 16) & 1u);
    return r & 0xFFFF0000u;
}

// ---------------------------------------------------------------------------
// mask table
// ---------------------------------------------------------------------------
__global__ void mask_tab_kernel(const float* __restrict__ s_v, float* __restrict__ tab) {
    int h = blockIdx.x;
    int idx = threadIdx.x;
    float w = expf(s_v[h]) + 1.0f;
    float rel = (float)(idx - 255);
    float val = 0.0f;
    if (rel > -w) {
        val = 0.5f * (cosf((float)M_PI * rel / w) + 1.0f);
    }
    tab[h * 256 + idx] = val;
}

// ---------------------------------------------------------------------------
// split_tiles: f32 [R][1024] row-major -> tiled f16 hi|lo planes (W only).
// Tile (rb, kt) = 16 KB: byte[row*128 + (c ^ ((row&7)<<4))].
// ---------------------------------------------------------------------------
__global__ __launch_bounds__(256) void split_tiles(
        const float* __restrict__ in0, const float* __restrict__ in1,
        const float* __restrict__ in2, char* __restrict__ out0,
        unsigned long long ostride) {
    const float* in = (blockIdx.y == 0) ? in0 : (blockIdx.y == 1) ? in1 : in2;
    char* outp = out0 + (size_t)blockIdx.y * ostride;
    const int tile = blockIdx.x;
    const int kt = tile & 31;
    const int rb = tile >> 5;
    const int tid = threadIdx.x;
    const int row = tid >> 1;
    const int kc = (tid & 1) * 16;

    const float* src = in + ((size_t)(rb * 128 + row)) * 1024 + kt * 32 + kc;
    f32x4 x0 = *(const f32x4*)src;
    f32x4 x1 = *(const f32x4*)(src + 4);
    f32x4 x2 = *(const f32x4*)(src + 8);
    f32x4 x3 = *(const f32x4*)(src + 12);
    float xs[16] = {x0[0], x0[1], x0[2], x0[3], x1[0], x1[1], x1[2], x1[3],
                    x2[0], x2[1], x2[2], x2[3], x3[0], x3[1], x3[2], x3[3]};
    F16U h0, h1, l0, l1;
#pragma unroll
    for (int e = 0; e < 8; e++) {
        _Float16 h = (_Float16)xs[e];
        h0.h[e] = h;
        l0.h[e] = (_Float16)(xs[e] - (float)h);
        _Float16 h2 = (_Float16)xs[8 + e];
        h1.h[e] = h2;
        l1.h[e] = (_Float16)(xs[8 + e] - (float)h2);
    }
    char* tb = outp + (size_t)tile * 16384 + row * 128;
    const int swz = (row & 7) << 4;
    *(uint4*)(tb + ((kc * 2) ^ swz))           = h0.u;
    *(uint4*)(tb + ((kc * 2 + 16) ^ swz))      = h1.u;
    *(uint4*)(tb + ((64 + kc * 2) ^ swz))      = l0.u;
    *(uint4*)(tb + ((64 + kc * 2 + 16) ^ swz)) = l1.u;
}

// ---------------------------------------------------------------------------
// cvt_split16: 16 f32 -> f16 hi/lo limb registers
// ---------------------------------------------------------------------------
__device__ __forceinline__ void cvt_split16(const f32x4* a, F16U& h0, F16U& h1,
                                            F16U& l0, F16U& l1) {
    float xs[16] = {a[0][0], a[0][1], a[0][2], a[0][3],
                    a[1][0], a[1][1], a[1][2], a[1][3],
                    a[2][0], a[2][1], a[2][2], a[2][3],
                    a[3][0], a[3][1], a[3][2], a[3][3]};
#pragma unroll
    for (int e = 0; e < 8; e++) {
        _Float16 h = (_Float16)xs[e];
        h0.h[e] = h;
        l0.h[e] = (_Float16)(xs[e] - (float)h);
        _Float16 h2 = (_Float16)xs[8 + e];
        h1.h[e] = h2;
        l1.h[e] = (_Float16)(xs[8 + e] - (float)h2);
    }
}

// ---------------------------------------------------------------------------
// gemm_ws (round-13/17 proven, ~165us QKV): C = A * W^T.  A f32 staged
// coalesced -> in-reg f16 split -> swizzled LDS; W via global_load_lds
// SINGLE buffer (32 KB) -> 48 KB LDS -> 3 blocks/CU -> all 768 QKV blocks
// co-resident in one generation.  launch_bounds(256,2): do NOT squeeze the
// allocator (round-12 lesson).
// Block 128x256, 4 waves (2x2), wave tile 64x128, 96 MFMA/wave/K-step.
// PERM=1: (B,H,T,D) output + fused per-head l2norm.
// ---------------------------------------------------------------------------
template <int PERM>
__global__ __launch_bounds__(256, 2) void gemm_ws(
        const float* __restrict__ A0, const float* __restrict__ A1,
        const float* __restrict__ A2,
        const char* __restrict__ Bsp, unsigned long long Bstride,
        float* __restrict__ C0, float* __restrict__ C1, float* __restrict__ C2) {
    __shared__ __align__(16) char Abuf[16384];
    __shared__ __align__(16) char Bbuf[32768];   // single-buffered

    const int tid = threadIdx.x;
    const int bid = blockIdx.x;
    const int o = bid >> 8;
    const int x = bid & 255;
    const int xcd = x & 7;
    const int idx = x >> 3;
    const int rp = xcd * 8 + (idx >> 2);
    const int cp = idx & 3;
    const int brow = rp * 128;
    const int bcol = cp * 256;

    const float* A = (o == 0) ? A0 : (o == 1) ? A1 : A2;
    float* C = (o == 0) ? C0 : (o == 1) ? C1 : C2;
    const char* Bt = Bsp + (size_t)o * Bstride;

    const int lane = tid & 63;
    const int wid = tid >> 6;
    const int wr = wid >> 1;
    const int wc = wid & 1;
    const int l15 = lane & 15;
    const int g = lane >> 4;

    const int srow = tid >> 1;
    const int skc2 = (tid & 1) * 32;
    const float* aptr = A + (size_t)(brow + srow) * 1024 + (tid & 1) * 16;
    const int aswz = (srow & 7) << 4;
    char* awr = Abuf + srow * 128;

    const char* bsrc = Bt + ((size_t)(cp * 2 + (wid >> 1)) * 32) * 16384
                       + (wid & 1) * 8192;

    const int rswz = (l15 & 7) << 4;

    f32x4 acc[4][8];
#pragma unroll
    for (int a = 0; a < 4; a++)
#pragma unroll
        for (int b = 0; b < 8; b++) acc[a][b] = (f32x4)(0.0f);

    // ---- prologue: A(0) regs->cvt; issue B(0); write A(0); drain ----
    f32x4 areg[4];
#pragma unroll
    for (int m = 0; m < 4; m++) areg[m] = *(const f32x4*)(aptr + m * 4);
    F16U Sh0, Sh1, Sl0, Sl1;
    cvt_split16(areg, Sh0, Sh1, Sl0, Sl1);
#pragma unroll
    for (int i = 0; i < 8; i++)
        __builtin_amdgcn_global_load_lds(
            (GVoid*)(bsrc + i * 1024 + lane * 16),
            (LVoid*)(Bbuf + wid * 8192 + i * 1024), 16, 0, 0);
    *(uint4*)(awr + ((skc2) ^ aswz))      = Sh0.u;
    *(uint4*)(awr + ((skc2 + 16) ^ aswz)) = Sh1.u;
    *(uint4*)(awr + ((skc2 + 64) ^ aswz)) = Sl0.u;
    *(uint4*)(awr + ((skc2 + 80) ^ aswz)) = Sl1.u;
    __syncthreads();                       // drains B(0) DMA + A(0) visible

#pragma unroll 1
    for (int kt = 0; kt < 32; kt++) {
        // prefetch A(kt+1) into regs (flies across compute)
        if (kt + 1 < 32) {
#pragma unroll
            for (int m = 0; m < 4; m++)
                areg[m] = *(const f32x4*)(aptr + (kt + 1) * 32 + m * 4);
        }

        const char* bb = Bbuf + wc * 16384;
        f16x8 ah[4], al[4];
#pragma unroll
        for (int fr = 0; fr < 4; fr++) {
            const int ro = (wr * 64 + fr * 16 + l15) * 128;
            ah[fr] = *(const f16x8*)(Abuf + ro + ((g * 16) ^ rswz));
            al[fr] = *(const f16x8*)(Abuf + ro + ((g * 16) ^ rswz ^ 64));
        }
#pragma unroll
        for (int fc = 0; fc < 8; fc++) {
            const int ro = (fc * 16 + l15) * 128;
            f16x8 bh = *(const f16x8*)(bb + ro + ((g * 16) ^ rswz));
            f16x8 bl = *(const f16x8*)(bb + ro + ((g * 16) ^ rswz ^ 64));
#pragma unroll
            for (int fr = 0; fr < 4; fr++) {
                acc[fr][fc] = __builtin_amdgcn_mfma_f32_16x16x32_f16(
                    ah[fr], bh, acc[fr][fc], 0, 0, 0);
                acc[fr][fc] = __builtin_amdgcn_mfma_f32_16x16x32_f16(
                    ah[fr], bl, acc[fr][fc], 0, 0, 0);
                acc[fr][fc] = __builtin_amdgcn_mfma_f32_16x16x32_f16(
                    al[fr], bh, acc[fr][fc], 0, 0, 0);
            }
        }

        if (kt + 1 < 32) {
            cvt_split16(areg, Sh0, Sh1, Sl0, Sl1);   // overlaps MFMA tail
            __syncthreads();               // all waves done reading Abuf/Bbuf
            const char* bs = bsrc + (size_t)(kt + 1) * 16384;
#pragma unroll
            for (int i = 0; i < 8; i++)
                __builtin_amdgcn_global_load_lds(
                    (GVoid*)(bs + i * 1024 + lane * 16),
                    (LVoid*)(Bbuf + wid * 8192 + i * 1024), 16, 0, 0);
            *(uint4*)(awr + ((skc2) ^ aswz))      = Sh0.u;
            *(uint4*)(awr + ((skc2 + 16) ^ aswz)) = Sh1.u;
            *(uint4*)(awr + ((skc2 + 64) ^ aswz)) = Sl0.u;
            *(uint4*)(awr + ((skc2 + 80) ^ aswz)) = Sl1.u;
            __syncthreads();               // drain B(kt+1) DMA + A visible
        }
    }

    if (PERM == 1) {
#pragma unroll
        for (int fr = 0; fr < 4; fr++) {
#pragma unroll
            for (int r = 0; r < 4; r++) {
                float p0 = 0.0f, p1 = 0.0f;
#pragma unroll
                for (int fc = 0; fc < 4; fc++) {
                    p0 = fmaf(acc[fr][fc][r], acc[fr][fc][r], p0);
                    p1 = fmaf(acc[fr][fc + 4][r], acc[fr][fc + 4][r], p1);
                }
                p0 += __shfl_xor(p0, 1);  p1 += __shfl_xor(p1, 1);
                p0 += __shfl_xor(p0, 2);  p1 += __shfl_xor(p1, 2);
                p0 += __shfl_xor(p0, 4);  p1 += __shfl_xor(p1, 4);
                p0 += __shfl_xor(p0, 8);  p1 += __shfl_xor(p1, 8);
                float i0 = 1.0f / fmaxf(sqrtf(p0), 1e-8f);
                float i1 = 1.0f / fmaxf(sqrtf(p1), 1e-8f);
#pragma unroll
                for (int fc = 0; fc < 4; fc++) {
                    acc[fr][fc][r] *= i0;
                    acc[fr][fc + 4][r] *= i1;
                }
            }
        }
    }

#pragma unroll
    for (int fr = 0; fr < 4; fr++) {
#pragma unroll
        for (int fc = 0; fc < 8; fc++) {
            f32x4 v = acc[fr][fc];
            const int i0 = brow + wr * 64 + fr * 16 + g * 4;
            const int j0 = bcol + wc * 128 + fc * 16;
            if (PERM == 0) {
#pragma unroll
                for (int r = 0; r < 4; r++)
                    C[(size_t)(i0 + r) * 1024 + j0 + l15] = v[r];
            } else {
                const int h = j0 >> 6;
                const int d = (j0 & 63) + l15;
#pragma unroll
                for (int r = 0; r < 4; r++) {
                    const int i = i0 + r;
                    const int b = i >> 12;
                    const int t2 = i & 4095;
                    C[(((size_t)(b * 16 + h) * 4096 + t2) * 64 + d)] = v[r];
                }
            }
        }
    }
}

// ---------------------------------------------------------------------------
// gemm_a2 (round-15/17 proven, ~36us): Wo projection (A = ao, L3-resident).
// Staged-A + issue-early double-buffered B.
// ---------------------------------------------------------------------------
template <int PERM>
__global__ __launch_bounds__(256, 2) void gemm_a2(
        const float* __restrict__ A0,
        const char* __restrict__ Bsp,
        float* __restrict__ C0) {
    __shared__ __align__(16) char Abuf[16384];
    __shared__ __align__(16) char Bbuf[32768];

    const int tid = threadIdx.x;
    const int x = blockIdx.x & 511;
    const int xcd = x & 7;
    const int idx = x >> 3;
    const int rp = xcd * 8 + (idx >> 3);
    const int cp = idx & 7;
    const int brow = rp * 128;
    const int bcol = cp * 128;

    const int lane = tid & 63;
    const int wid = tid >> 6;
    const int wr = wid >> 1;
    const int wc = wid & 1;
    const int l15 = lane & 15;
    const int g = lane >> 4;

    const int srow = tid >> 1;
    const int skc2 = (tid & 1) * 32;
    const float* aptr = A0 + (size_t)(brow + srow) * 1024 + (tid & 1) * 16;
    const int aswz = (srow & 7) << 4;
    char* awr = Abuf + srow * 128;

    const char* bsrc = Bsp + ((size_t)cp * 32) * 16384 + wid * 4096;

    const int rswz = (l15 & 7) << 4;

    f32x4 acc[4][4];
#pragma unroll
    for (int a = 0; a < 4; a++)
#pragma unroll
        for (int b = 0; b < 4; b++) acc[a][b] = (f32x4)(0.0f);

    f32x4 areg[4];
    F16U Sh0, Sh1, Sl0, Sl1;

#define ISSUE_B(KT, WB)                                                        \
    do {                                                                       \
        const char* bs_ = bsrc + (size_t)(KT) * 16384;                         \
        _Pragma("unroll") for (int i = 0; i < 4; i++)                          \
            __builtin_amdgcn_global_load_lds(                                  \
                (GVoid*)(bs_ + i * 1024 + lane * 16),                          \
                (LVoid*)(Bbuf + (WB) * 16384 + wid * 4096 + i * 1024),         \
                16, 0, 0);                                                     \
    } while (0)

#define LOADA(KA)                                                              \
    do {                                                                       \
        _Pragma("unroll") for (int m = 0; m < 4; m++)                          \
            areg[m] = *(const f32x4*)(aptr + (KA) * 32 + m * 4);               \
    } while (0)

#define WRITEA()                                                               \
    do {                                                                       \
        *(uint4*)(awr + ((skc2) ^ aswz))      = Sh0.u;                         \
        *(uint4*)(awr + ((skc2 + 16) ^ aswz)) = Sh1.u;                         \
        *(uint4*)(awr + ((skc2 + 64) ^ aswz)) = Sl0.u;                         \
        *(uint4*)(awr + ((skc2 + 80) ^ aswz)) = Sl1.u;                         \
    } while (0)

#define COMPUTE(RB)                                                            \
    do {                                                                       \
        const char* bb_ = Bbuf + (RB) * 16384;                                 \
        f16x8 ah_[4], al_[4];                                                  \
        _Pragma("unroll") for (int fr = 0; fr < 4; fr++) {                     \
            const int ro_ = (wr * 64 + fr * 16 + l15) * 128;                   \
            ah_[fr] = *(const f16x8*)(Abuf + ro_ + ((g * 16) ^ rswz));         \
            al_[fr] = *(const f16x8*)(Abuf + ro_ + ((g * 16) ^ rswz ^ 64));    \
        }                                                                      \
        _Pragma("unroll") for (int fc = 0; fc < 4; fc++) {                     \
            const int ro_ = (wc * 64 + fc * 16 + l15) * 128;                   \
            f16x8 bh_ = *(const f16x8*)(bb_ + ro_ + ((g * 16) ^ rswz));        \
            f16x8 bl_ = *(const f16x8*)(bb_ + ro_ + ((g * 16) ^ rswz ^ 64));   \
            _Pragma("unroll") for (int fr = 0; fr < 4; fr++) {                 \
                acc[fr][fc] = __builtin_amdgcn_mfma_f32_16x16x32_f16(          \
                    ah_[fr], bh_, acc[fr][fc], 0, 0, 0);                       \
                acc[fr][fc] = __builtin_amdgcn_mfma_f32_16x16x32_f16(          \
                    ah_[fr], bl_, acc[fr][fc], 0, 0, 0);                       \
                acc[fr][fc] = __builtin_amdgcn_mfma_f32_16x16x32_f16(          \
                    al_[fr], bh_, acc[fr][fc], 0, 0, 0);                       \
            }                                                                  \
        }                                                                      \
    } while (0)

    LOADA(0);
    cvt_split16(areg, Sh0, Sh1, Sl0, Sl1);
    ISSUE_B(0, 0);
    WRITEA();
    __syncthreads();

#pragma unroll 1
    for (int kt = 0; kt < 32; kt += 2) {
        ISSUE_B(kt + 1, 1);
        LOADA(kt + 1);
        COMPUTE(0);
        cvt_split16(areg, Sh0, Sh1, Sl0, Sl1);
        __syncthreads();
        WRITEA();
        __syncthreads();
        if (kt + 2 < 32) { ISSUE_B(kt + 2, 0); LOADA(kt + 2); }
        COMPUTE(1);
        if (kt + 2 < 32) {
            cvt_split16(areg, Sh0, Sh1, Sl0, Sl1);
            __syncthreads();
            WRITEA();
            __syncthreads();
        }
    }

#undef COMPUTE
#undef WRITEA
#undef LOADA
#undef ISSUE_B

#pragma unroll
    for (int fr = 0; fr < 4; fr++) {
#pragma unroll
        for (int fc = 0; fc < 4; fc++) {
            f32x4 v = acc[fr][fc];
            const int i0 = brow + wr * 64 + fr * 16 + g * 4;
            const int j0 = bcol + wc * 64 + fc * 16;
#pragma unroll
            for (int r = 0; r < 4; r++)
                C0[(size_t)(i0 + r) * 1024 + j0 + l15] = v[r];
        }
    }
}

// ---------------------------------------------------------------------------
// MFMA banded attention (round-7 structure + r18 setprio) with the K/V
// prefetch moved AFTER sync2: previously the next-tile global loads were
// issued right before __syncthreads (whose vmcnt(0) drain waited on them,
// fully exposed).  Issued after sync2 they fly across the compute phase and
// are drained at next iteration's sync1 (covered).  Same regs, same barriers,
// same arithmetic.
// ---------------------------------------------------------------------------
__global__ __launch_bounds__(256, 3) void attn_kernel(
        const float* __restrict__ q, const float* __restrict__ k,
        const float* __restrict__ v, const float* __restrict__ s_v,
        const float* __restrict__ s_r, const float* __restrict__ mask_tab,
        float* __restrict__ out) {
    __shared__ unsigned short Kh[32 * 72];
    __shared__ unsigned short Kl[32 * 72];
    __shared__ unsigned short Vh[64 * 40];
    __shared__ unsigned short Vl[64 * 40];
    __shared__ unsigned int   aB[4][32 * 33];
    __shared__ float          msk[256];

    const int bx = blockIdx.x;
    const int h   = bx & 15;
    const int n   = (bx >> 4) & 15;
    const int sub = (bx >> 8) & 1;
    const int b   = bx >> 9;
    const int bh = b * 16 + h;
    const int tid = threadIdx.x;
    const int lane = tid & 63;
    const int wid = tid >> 6;
    const int l15 = lane & 15;
    const int g = lane >> 4;

    msk[tid] = mask_tab[h * 256 + tid];
    const float w = expf(s_v[h]) + 1.0f;
    const float rh = expf(s_r[h]) + 1.0f;

    const int row0 = n * 256 + sub * 128;
    const float* qbase = q + (size_t)bh * 4096 * 64;
    const float* kbase = k + (size_t)bh * 4096 * 64;
    const float* vbase = v + (size_t)bh * 4096 * 64;

    bf16x8 qh[2][2], ql[2][2];
#pragma unroll
    for (int f = 0; f < 2; f++) {
#pragma unroll
        for (int ks = 0; ks < 2; ks++) {
            const float* src = qbase + (size_t)(row0 + wid * 32 + f * 16 + l15) * 64
                               + ks * 32 + g * 8;
            f32x4 x0 = *(const f32x4*)src;
            f32x4 x1 = *(const f32x4*)(src + 4);
            float xs[8] = {x0[0], x0[1], x0[2], x0[3], x1[0], x1[1], x1[2], x1[3]};
            unsigned hb[8], lb[8];
#pragma unroll
            for (int e = 0; e < 8; e++) {
                hb[e] = rn_hi(xs[e]);
                lb[e] = rn_hi(xs[e] - __uint_as_float(hb[e]));
            }
            FragU th, tl;
            th.u = make_uint4((hb[0] >> 16) | hb[1], (hb[2] >> 16) | hb[3],
                              (hb[4] >> 16) | hb[5], (hb[6] >> 16) | hb[7]);
            tl.u = make_uint4((lb[0] >> 16) | lb[1], (lb[2] >> 16) | lb[3],
                              (lb[4] >> 16) | lb[5], (lb[6] >> 16) | lb[7]);
            qh[f][ks] = th.f;
            ql[f][ks] = tl.f;
        }
    }

    int jlo = (int)floorf(256.0f + (float)(sub * 128) - w) + 1;
    if (jlo < 0) jlo = 0;
    if (n == 0 && jlo < 256) jlo = 256;
    jlo &= ~31;
    const int jhi = 256 + sub * 128 + 127;

    const int iw0 = sub * 128 + wid * 32;

    f32x4 acc[2][4];
#pragma unroll
    for (int a = 0; a < 2; a++)
#pragma unroll
        for (int d = 0; d < 4; d++) acc[a][d] = (f32x4)(0.0f);

    const int kj = tid >> 3;
    const int kd = (tid & 7) * 8;
    const int vj = tid & 31;
    const int vd = (tid >> 5) * 8;

    f32x4 kr0, kr1, vr0, vr1;
    {
        const float* ks = kbase + (size_t)((n - 1) * 256 + jlo + kj) * 64 + kd;
        const float* vs = vbase + (size_t)((n - 1) * 256 + jlo + vj) * 64 + vd;
        kr0 = *(const f32x4*)ks;  kr1 = *(const f32x4*)(ks + 4);
        vr0 = *(const f32x4*)vs;  vr1 = *(const f32x4*)(vs + 4);
    }

    for (int jt = jlo; jt <= jhi; jt += 32) {
        __syncthreads();                   // sync1: prev reads done; drains prefetch
        {
            float xs[8] = {kr0[0], kr0[1], kr0[2], kr0[3], kr1[0], kr1[1], kr1[2], kr1[3]};
            unsigned hb[8], lb[8];
#pragma unroll
            for (int e = 0; e < 8; e++) {
                hb[e] = rn_hi(xs[e]);
                lb[e] = rn_hi(xs[e] - __uint_as_float(hb[e]));
            }
            *(uint4*)&Kh[kj * 72 + kd] =
                make_uint4((hb[0] >> 16) | hb[1], (hb[2] >> 16) | hb[3],
                           (hb[4] >> 16) | hb[5], (hb[6] >> 16) | hb[7]);
            *(uint4*)&Kl[kj * 72 + kd] =
                make_uint4((lb[0] >> 16) | lb[1], (lb[2] >> 16) | lb[3],
                           (lb[4] >> 16) | lb[5], (lb[6] >> 16) | lb[7]);
        }
        {
            float xs[8] = {vr0[0], vr0[1], vr0[2], vr0[3], vr1[0], vr1[1], vr1[2], vr1[3]};
#pragma unroll
            for (int e = 0; e < 8; e++) {
                unsigned hbv = rn_hi(xs[e]);
                unsigned lbv = rn_hi(xs[e] - __uint_as_float(hbv));
                Vh[(vd + e) * 40 + vj] = (unsigned short)(hbv >> 16);
                Vl[(vd + e) * 40 + vj] = (unsigned short)(lbv >> 16);
            }
        }
        __syncthreads();                   // sync2: tiles visible (no loads pending)

        // prefetch next tile AFTER sync2: flies across compute, drained at
        // next sync1 (covered by compute) instead of at sync2 (exposed).
        if (jt + 32 <= jhi) {
            const float* ks = kbase + (size_t)((n - 1) * 256 + jt + 32 + kj) * 64 + kd;
            const float* vs = vbase + (size_t)((n - 1) * 256 + jt + 32 + vj) * 64 + vd;
            kr0 = *(const f32x4*)ks;  kr1 = *(const f32x4*)(ks + 4);
            vr0 = *(const f32x4*)vs;  vr1 = *(const f32x4*)(vs + 4);
        }

        const bool live = ((float)(jt + 31) > 256.0f + (float)iw0 - w) &&
                          (jt <= 256 + iw0 + 31);
        if (live) {
            f32x4 sim[2][2];
#pragma unroll
            for (int jf = 0; jf < 2; jf++)
#pragma unroll
                for (int f = 0; f < 2; f++) sim[jf][f] = (f32x4)(0.0f);

            __builtin_amdgcn_s_setprio(1);
#pragma unroll
            for (int jf = 0; jf < 2; jf++) {
#pragma unroll
                for (int ks = 0; ks < 2; ks++) {
                    bf16x8 kah = *(const bf16x8*)&Kh[(jf * 16 + l15) * 72 + ks * 32 + g * 8];
                    bf16x8 kal = *(const bf16x8*)&Kl[(jf * 16 + l15) * 72 + ks * 32 + g * 8];
#pragma unroll
                    for (int f = 0; f < 2; f++) {
                        sim[jf][f] = __builtin_amdgcn_mfma_f32_16x16x32_bf16(
                            kah, qh[f][ks], sim[jf][f], 0, 0, 0);
                        sim[jf][f] = __builtin_amdgcn_mfma_f32_16x16x32_bf16(
                            kah, ql[f][ks], sim[jf][f], 0, 0, 0);
                        sim[jf][f] = __builtin_amdgcn_mfma_f32_16x16x32_bf16(
                            kal, qh[f][ks], sim[jf][f], 0, 0, 0);
                    }
                }
            }
            __builtin_amdgcn_s_setprio(0);

#pragma unroll
            for (int jf = 0; jf < 2; jf++) {
#pragma unroll
                for (int f = 0; f < 2; f++) {
#pragma unroll
                    for (int r = 0; r < 4; r++) {
                        const int jloc = jf * 16 + g * 4 + r;
                        const int iloc = f * 16 + l15;
                        const int relv = (jt + jloc) - 256 - (sub * 128 + wid * 32 + iloc);
                        float m = (relv >= -255 && relv <= 0) ? msk[relv + 255] : 0.0f;
                        float t1 = 1.0f - rh * (1.0f - sim[jf][f][r]);
                        t1 = fmaxf(t1, 0.0f);
                        float alpha = t1 * t1 * m;
                        unsigned ahb = rn_hi(alpha);
                        unsigned alb = rn_hi(alpha - __uint_as_float(ahb));
                        aB[wid][jloc * 33 + iloc] = ahb | (alb >> 16);
                    }
                }
            }

#pragma unroll
            for (int f = 0; f < 2; f++) {
                unsigned a8[8];
#pragma unroll
                for (int e = 0; e < 8; e++)
                    a8[e] = aB[wid][(g * 8 + e) * 33 + f * 16 + l15];
                FragU th, tl;
                th.u = make_uint4((a8[0] >> 16) | (a8[1] & 0xFFFF0000u),
                                  (a8[2] >> 16) | (a8[3] & 0xFFFF0000u),
                                  (a8[4] >> 16) | (a8[5] & 0xFFFF0000u),
                                  (a8[6] >> 16) | (a8[7] & 0xFFFF0000u));
                tl.u = make_uint4((a8[0] << 16 >> 16) | (a8[1] << 16),
                                  (a8[2] << 16 >> 16) | (a8[3] << 16),
                                  (a8[4] << 16 >> 16) | (a8[5] << 16),
                                  (a8[6] << 16 >> 16) | (a8[7] << 16));
                bf16x8 aah = th.f, aal = tl.f;
                __builtin_amdgcn_s_setprio(1);
#pragma unroll
                for (int df = 0; df < 4; df++) {
                    bf16x8 vbh = *(const bf16x8*)&Vh[(df * 16 + l15) * 40 + g * 8];
                    bf16x8 vbl = *(const bf16x8*)&Vl[(df * 16 + l15) * 40 + g * 8];
                    acc[f][df] = __builtin_amdgcn_mfma_f32_16x16x32_bf16(
                        aah, vbh, acc[f][df], 0, 0, 0);
                    acc[f][df] = __builtin_amdgcn_mfma_f32_16x16x32_bf16(
                        aah, vbl, acc[f][df], 0, 0, 0);
                    acc[f][df] = __builtin_amdgcn_mfma_f32_16x16x32_bf16(
                        aal, vbh, acc[f][df], 0, 0, 0);
                }
                __builtin_amdgcn_s_setprio(0);
            }
        }
    }

#pragma unroll
    for (int f = 0; f < 2; f++) {
#pragma unroll
        for (int r = 0; r < 4; r++) {
            float p = 0.0f;
#pragma unroll
            for (int df = 0; df < 4; df++) p = fmaf(acc[f][df][r], acc[f][df][r], p);
            p += __shfl_xor(p, 1);
            p += __shfl_xor(p, 2);
            p += __shfl_xor(p, 4);
            p += __shfl_xor(p, 8);
            float nn = sqrtf(p);
            float sc = tanhf(nn) / (nn + 1e-8f);
            const int trow = row0 + wid * 32 + f * 16 + g * 4 + r;
            float* dst = out + ((size_t)(b * 4096 + trow)) * 1024 + h * 64;
#pragma unroll
            for (int df = 0; df < 4; df++)
                dst[df * 16 + l15] = acc[f][df][r] * sc;
        }
    }
}

// ---------------------------------------------------------------------------
// Workspace layout (peak = 128MB + 16KB, proven):
//   [0,96)MB   : qw/kw/vw; later reused: [0,4)MB = Wo split
//   [96,128)MB : Wq/Wk/Wv split planes (12MB, dead pre-attn) then ao (32MB)
//   [128MB,+16KB) : mask
// ---------------------------------------------------------------------------
extern "C" void kernel_launch(void* const* d_in, const int* in_sizes, int n_in,
                              void* d_out, int out_size, void* d_ws, size_t ws_size,
                              hipStream_t stream) {
    const float* query = (const float*)d_in[0];
    const float* key   = (const float*)d_in[1];
    const float* value = (const float*)d_in[2];
    const float* Wq    = (const float*)d_in[3];
    const float* Wk    = (const float*)d_in[4];
    const float* Wv    = (const float*)d_in[5];
    const float* Wo    = (const float*)d_in[6];
    const float* s_v   = (const float*)d_in[7];
    const float* s_r   = (const float*)d_in[8];
    float* out = (float*)d_out;

    const size_t MB = 1ull << 20;
    char* base = (char*)d_ws;
    float* qw   = (float*)(base);
    float* kw   = (float*)(base + 32 * MB);
    float* vw   = (float*)(base + 64 * MB);
    float* ao   = (float*)(base + 96 * MB);
    char*  w3sp = base + 96 * MB;           // aliases ao (dead before attn)
    char*  wosp = base;                     // aliases qw (written after attn)
    float* mask = (float*)(base + 128 * MB);

    mask_tab_kernel<<<dim3(16), dim3(256), 0, stream>>>(s_v, mask);

    // pre-split Wq/Wk/Wv into the (not-yet-written) ao region
    split_tiles<<<dim3(256, 3), dim3(256), 0, stream>>>(Wq, Wk, Wv, w3sp, 4 * MB);

    // fused QKV projections + l2norm (round-13 proven gemm_ws, 48KB LDS)
    gemm_ws<1><<<dim3(768), dim3(256), 0, stream>>>(
        query, key, value, w3sp, 4 * MB, qw, kw, vw);

    // banded attention (proven version + setprio + covered prefetch)
    attn_kernel<<<dim3(1024), dim3(256), 0, stream>>>(
        qw, kw, vw, s_v, s_r, mask, ao);

    // pre-split Wo into the (now-dead) qw region
    split_tiles<<<dim3(256, 1), dim3(256), 0, stream>>>(Wo, Wo, Wo, wosp, 0);

    // output projection (round-15 proven gemm_a2, A = L3-resident ao)
    gemm_a2<0><<<dim3(512), dim3(256), 0, stream>>>(ao, wosp, out);
}

// Round 20
// 287.425 us; speedup vs baseline: 1.0027x; 1.0027x over previous
//
#include <hip/hip_runtime.h>
#include <math.h>

#ifndef M_PI
#define M_PI 3.14159265358979323846
#endif

typedef short bf16x8 __attribute__((ext_vector_type(8)));
typedef _Float16 f16x8 __attribute__((ext_vector_type(8)));
typedef float f32x4 __attribute__((ext_vector_type(4)));

union FragU { uint4 u; bf16x8 f; };
union F16U { uint4 u; f16x8 f; _Float16 h[8]; };

typedef const __attribute__((address_space(1))) void GVoid;
typedef __attribute__((address_space(3))) void LVoid;

// round-to-nearest-even bf16, returned as bits in HIGH 16 (low 16 zero)
__device__ __forceinline__ unsigned rn_hi(float x) {
    unsigned u = __float_as_uint(x);
    unsigned r = u + 0x7FFFu + ((u >> 16) & 1u);
    return r & 0xFFFF0000u;
}

// ---------------------------------------------------------------------------
// mask table
// ---------------------------------------------------------------------------
__global__ void mask_tab_kernel(const float* __restrict__ s_v, float* __restrict__ tab) {
    int h = blockIdx.x;
    int idx = threadIdx.x;
    float w = expf(s_v[h]) + 1.0f;
    float rel = (float)(idx - 255);
    float val = 0.0f;
    if (rel > -w) {
        val = 0.5f * (cosf((float)M_PI * rel / w) + 1.0f);
    }
    tab[h * 256 + idx] = val;
}

// ---------------------------------------------------------------------------
// split_tiles: f32 [R][1024] row-major -> tiled f16 hi|lo planes (W only).
// Tile (rb, kt) = 16 KB: byte[row*128 + (c ^ ((row&7)<<4))].
// ---------------------------------------------------------------------------
__global__ __launch_bounds__(256) void split_tiles(
        const float* __restrict__ in0, const float* __restrict__ in1,
        const float* __restrict__ in2, char* __restrict__ out0,
        unsigned long long ostride) {
    const float* in = (blockIdx.y == 0) ? in0 : (blockIdx.y == 1) ? in1 : in2;
    char* outp = out0 + (size_t)blockIdx.y * ostride;
    const int tile = blockIdx.x;
    const int kt = tile & 31;
    const int rb = tile >> 5;
    const int tid = threadIdx.x;
    const int row = tid >> 1;
    const int kc = (tid & 1) * 16;

    const float* src = in + ((size_t)(rb * 128 + row)) * 1024 + kt * 32 + kc;
    f32x4 x0 = *(const f32x4*)src;
    f32x4 x1 = *(const f32x4*)(src + 4);
    f32x4 x2 = *(const f32x4*)(src + 8);
    f32x4 x3 = *(const f32x4*)(src + 12);
    float xs[16] = {x0[0], x0[1], x0[2], x0[3], x1[0], x1[1], x1[2], x1[3],
                    x2[0], x2[1], x2[2], x2[3], x3[0], x3[1], x3[2], x3[3]};
    F16U h0, h1, l0, l1;
#pragma unroll
    for (int e = 0; e < 8; e++) {
        _Float16 h = (_Float16)xs[e];
        h0.h[e] = h;
        l0.h[e] = (_Float16)(xs[e] - (float)h);
        _Float16 h2 = (_Float16)xs[8 + e];
        h1.h[e] = h2;
        l1.h[e] = (_Float16)(xs[8 + e] - (float)h2);
    }
    char* tb = outp + (size_t)tile * 16384 + row * 128;
    const int swz = (row & 7) << 4;
    *(uint4*)(tb + ((kc * 2) ^ swz))           = h0.u;
    *(uint4*)(tb + ((kc * 2 + 16) ^ swz))      = h1.u;
    *(uint4*)(tb + ((64 + kc * 2) ^ swz))      = l0.u;
    *(uint4*)(tb + ((64 + kc * 2 + 16) ^ swz)) = l1.u;
}

// ---------------------------------------------------------------------------
// cvt_split16: 16 f32 -> f16 hi/lo limb registers
// ---------------------------------------------------------------------------
__device__ __forceinline__ void cvt_split16(const f32x4* a, F16U& h0, F16U& h1,
                                            F16U& l0, F16U& l1) {
    float xs[16] = {a[0][0], a[0][1], a[0][2], a[0][3],
                    a[1][0], a[1][1], a[1][2], a[1][3],
                    a[2][0], a[2][1], a[2][2], a[2][3],
                    a[3][0], a[3][1], a[3][2], a[3][3]};
#pragma unroll
    for (int e = 0; e < 8; e++) {
        _Float16 h = (_Float16)xs[e];
        h0.h[e] = h;
        l0.h[e] = (_Float16)(xs[e] - (float)h);
        _Float16 h2 = (_Float16)xs[8 + e];
        h1.h[e] = h2;
        l1.h[e] = (_Float16)(xs[8 + e] - (float)h2);
    }
}

// ---------------------------------------------------------------------------
// gemm_ws (round-13/17/18 proven, ~165us QKV): C = A * W^T.  A f32 staged
// coalesced -> in-reg f16 split -> swizzled LDS; W via global_load_lds
// SINGLE buffer (32 KB) -> 48 KB LDS -> 3 blocks/CU -> all 768 QKV blocks
// co-resident in one generation.  launch_bounds(256,2).
// Block 128x256, 4 waves (2x2), wave tile 64x128, 96 MFMA/wave/K-step.
// PERM=1: (B,H,T,D) output + fused per-head l2norm.
// ---------------------------------------------------------------------------
template <int PERM>
__global__ __launch_bounds__(256, 2) void gemm_ws(
        const float* __restrict__ A0, const float* __restrict__ A1,
        const float* __restrict__ A2,
        const char* __restrict__ Bsp, unsigned long long Bstride,
        float* __restrict__ C0, float* __restrict__ C1, float* __restrict__ C2) {
    __shared__ __align__(16) char Abuf[16384];
    __shared__ __align__(16) char Bbuf[32768];   // single-buffered

    const int tid = threadIdx.x;
    const int bid = blockIdx.x;
    const int o = bid >> 8;
    const int x = bid & 255;
    const int xcd = x & 7;
    const int idx = x >> 3;
    const int rp = xcd * 8 + (idx >> 2);
    const int cp = idx & 3;
    const int brow = rp * 128;
    const int bcol = cp * 256;

    const float* A = (o == 0) ? A0 : (o == 1) ? A1 : A2;
    float* C = (o == 0) ? C0 : (o == 1) ? C1 : C2;
    const char* Bt = Bsp + (size_t)o * Bstride;

    const int lane = tid & 63;
    const int wid = tid >> 6;
    const int wr = wid >> 1;
    const int wc = wid & 1;
    const int l15 = lane & 15;
    const int g = lane >> 4;

    const int srow = tid >> 1;
    const int skc2 = (tid & 1) * 32;
    const float* aptr = A + (size_t)(brow + srow) * 1024 + (tid & 1) * 16;
    const int aswz = (srow & 7) << 4;
    char* awr = Abuf + srow * 128;

    const char* bsrc = Bt + ((size_t)(cp * 2 + (wid >> 1)) * 32) * 16384
                       + (wid & 1) * 8192;

    const int rswz = (l15 & 7) << 4;

    f32x4 acc[4][8];
#pragma unroll
    for (int a = 0; a < 4; a++)
#pragma unroll
        for (int b = 0; b < 8; b++) acc[a][b] = (f32x4)(0.0f);

    // ---- prologue: A(0) regs->cvt; issue B(0); write A(0); drain ----
    f32x4 areg[4];
#pragma unroll
    for (int m = 0; m < 4; m++) areg[m] = *(const f32x4*)(aptr + m * 4);
    F16U Sh0, Sh1, Sl0, Sl1;
    cvt_split16(areg, Sh0, Sh1, Sl0, Sl1);
#pragma unroll
    for (int i = 0; i < 8; i++)
        __builtin_amdgcn_global_load_lds(
            (GVoid*)(bsrc + i * 1024 + lane * 16),
            (LVoid*)(Bbuf + wid * 8192 + i * 1024), 16, 0, 0);
    *(uint4*)(awr + ((skc2) ^ aswz))      = Sh0.u;
    *(uint4*)(awr + ((skc2 + 16) ^ aswz)) = Sh1.u;
    *(uint4*)(awr + ((skc2 + 64) ^ aswz)) = Sl0.u;
    *(uint4*)(awr + ((skc2 + 80) ^ aswz)) = Sl1.u;
    __syncthreads();                       // drains B(0) DMA + A(0) visible

#pragma unroll 1
    for (int kt = 0; kt < 32; kt++) {
        // prefetch A(kt+1) into regs (flies across compute)
        if (kt + 1 < 32) {
#pragma unroll
            for (int m = 0; m < 4; m++)
                areg[m] = *(const f32x4*)(aptr + (kt + 1) * 32 + m * 4);
        }

        const char* bb = Bbuf + wc * 16384;
        f16x8 ah[4], al[4];
#pragma unroll
        for (int fr = 0; fr < 4; fr++) {
            const int ro = (wr * 64 + fr * 16 + l15) * 128;
            ah[fr] = *(const f16x8*)(Abuf + ro + ((g * 16) ^ rswz));
            al[fr] = *(const f16x8*)(Abuf + ro + ((g * 16) ^ rswz ^ 64));
        }
#pragma unroll
        for (int fc = 0; fc < 8; fc++) {
            const int ro = (fc * 16 + l15) * 128;
            f16x8 bh = *(const f16x8*)(bb + ro + ((g * 16) ^ rswz));
            f16x8 bl = *(const f16x8*)(bb + ro + ((g * 16) ^ rswz ^ 64));
#pragma unroll
            for (int fr = 0; fr < 4; fr++) {
                acc[fr][fc] = __builtin_amdgcn_mfma_f32_16x16x32_f16(
                    ah[fr], bh, acc[fr][fc], 0, 0, 0);
                acc[fr][fc] = __builtin_amdgcn_mfma_f32_16x16x32_f16(
                    ah[fr], bl, acc[fr][fc], 0, 0, 0);
                acc[fr][fc] = __builtin_amdgcn_mfma_f32_16x16x32_f16(
                    al[fr], bh, acc[fr][fc], 0, 0, 0);
            }
        }

        if (kt + 1 < 32) {
            cvt_split16(areg, Sh0, Sh1, Sl0, Sl1);   // overlaps MFMA tail
            __syncthreads();               // all waves done reading Abuf/Bbuf
            const char* bs = bsrc + (size_t)(kt + 1) * 16384;
#pragma unroll
            for (int i = 0; i < 8; i++)
                __builtin_amdgcn_global_load_lds(
                    (GVoid*)(bs + i * 1024 + lane * 16),
                    (LVoid*)(Bbuf + wid * 8192 + i * 1024), 16, 0, 0);
            *(uint4*)(awr + ((skc2) ^ aswz))      = Sh0.u;
            *(uint4*)(awr + ((skc2 + 16) ^ aswz)) = Sh1.u;
            *(uint4*)(awr + ((skc2 + 64) ^ aswz)) = Sl0.u;
            *(uint4*)(awr + ((skc2 + 80) ^ aswz)) = Sl1.u;
            __syncthreads();               // drain B(kt+1) DMA + A visible
        }
    }

    if (PERM == 1) {
#pragma unroll
        for (int fr = 0; fr < 4; fr++) {
#pragma unroll
            for (int r = 0; r < 4; r++) {
                float p0 = 0.0f, p1 = 0.0f;
#pragma unroll
                for (int fc = 0; fc < 4; fc++) {
                    p0 = fmaf(acc[fr][fc][r], acc[fr][fc][r], p0);
                    p1 = fmaf(acc[fr][fc + 4][r], acc[fr][fc + 4][r], p1);
                }
                p0 += __shfl_xor(p0, 1);  p1 += __shfl_xor(p1, 1);
                p0 += __shfl_xor(p0, 2);  p1 += __shfl_xor(p1, 2);
                p0 += __shfl_xor(p0, 4);  p1 += __shfl_xor(p1, 4);
                p0 += __shfl_xor(p0, 8);  p1 += __shfl_xor(p1, 8);
                float i0 = 1.0f / fmaxf(sqrtf(p0), 1e-8f);
                float i1 = 1.0f / fmaxf(sqrtf(p1), 1e-8f);
#pragma unroll
                for (int fc = 0; fc < 4; fc++) {
                    acc[fr][fc][r] *= i0;
                    acc[fr][fc + 4][r] *= i1;
                }
            }
        }
    }

#pragma unroll
    for (int fr = 0; fr < 4; fr++) {
#pragma unroll
        for (int fc = 0; fc < 8; fc++) {
            f32x4 v = acc[fr][fc];
            const int i0 = brow + wr * 64 + fr * 16 + g * 4;
            const int j0 = bcol + wc * 128 + fc * 16;
            if (PERM == 0) {
#pragma unroll
                for (int r = 0; r < 4; r++)
                    C[(size_t)(i0 + r) * 1024 + j0 + l15] = v[r];
            } else {
                const int h = j0 >> 6;
                const int d = (j0 & 63) + l15;
#pragma unroll
                for (int r = 0; r < 4; r++) {
                    const int i = i0 + r;
                    const int b = i >> 12;
                    const int t2 = i & 4095;
                    C[(((size_t)(b * 16 + h) * 4096 + t2) * 64 + d)] = v[r];
                }
            }
        }
    }
}

// ---------------------------------------------------------------------------
// gemm_a2 (round-15/17/18 proven, ~36us): Wo projection (A = ao, L3-resident).
// Staged-A + issue-early double-buffered B.
// ---------------------------------------------------------------------------
template <int PERM>
__global__ __launch_bounds__(256, 2) void gemm_a2(
        const float* __restrict__ A0,
        const char* __restrict__ Bsp,
        float* __restrict__ C0) {
    __shared__ __align__(16) char Abuf[16384];
    __shared__ __align__(16) char Bbuf[32768];

    const int tid = threadIdx.x;
    const int x = blockIdx.x & 511;
    const int xcd = x & 7;
    const int idx = x >> 3;
    const int rp = xcd * 8 + (idx >> 3);
    const int cp = idx & 7;
    const int brow = rp * 128;
    const int bcol = cp * 128;

    const int lane = tid & 63;
    const int wid = tid >> 6;
    const int wr = wid >> 1;
    const int wc = wid & 1;
    const int l15 = lane & 15;
    const int g = lane >> 4;

    const int srow = tid >> 1;
    const int skc2 = (tid & 1) * 32;
    const float* aptr = A0 + (size_t)(brow + srow) * 1024 + (tid & 1) * 16;
    const int aswz = (srow & 7) << 4;
    char* awr = Abuf + srow * 128;

    const char* bsrc = Bsp + ((size_t)cp * 32) * 16384 + wid * 4096;

    const int rswz = (l15 & 7) << 4;

    f32x4 acc[4][4];
#pragma unroll
    for (int a = 0; a < 4; a++)
#pragma unroll
        for (int b = 0; b < 4; b++) acc[a][b] = (f32x4)(0.0f);

    f32x4 areg[4];
    F16U Sh0, Sh1, Sl0, Sl1;

#define ISSUE_B(KT, WB)                                                        \
    do {                                                                       \
        const char* bs_ = bsrc + (size_t)(KT) * 16384;                         \
        _Pragma("unroll") for (int i = 0; i < 4; i++)                          \
            __builtin_amdgcn_global_load_lds(                                  \
                (GVoid*)(bs_ + i * 1024 + lane * 16),                          \
                (LVoid*)(Bbuf + (WB) * 16384 + wid * 4096 + i * 1024),         \
                16, 0, 0);                                                     \
    } while (0)

#define LOADA(KA)                                                              \
    do {                                                                       \
        _Pragma("unroll") for (int m = 0; m < 4; m++)                          \
            areg[m] = *(const f32x4*)(aptr + (KA) * 32 + m * 4);               \
    } while (0)

#define WRITEA()                                                               \
    do {                                                                       \
        *(uint4*)(awr + ((skc2) ^ aswz))      = Sh0.u;                         \
        *(uint4*)(awr + ((skc2 + 16) ^ aswz)) = Sh1.u;                         \
        *(uint4*)(awr + ((skc2 + 64) ^ aswz)) = Sl0.u;                         \
        *(uint4*)(awr + ((skc2 + 80) ^ aswz)) = Sl1.u;                         \
    } while (0)

#define COMPUTE(RB)                                                            \
    do {                                                                       \
        const char* bb_ = Bbuf + (RB) * 16384;                                 \
        f16x8 ah_[4], al_[4];                                                  \
        _Pragma("unroll") for (int fr = 0; fr < 4; fr++) {                     \
            const int ro_ = (wr * 64 + fr * 16 + l15) * 128;                   \
            ah_[fr] = *(const f16x8*)(Abuf + ro_ + ((g * 16) ^ rswz));         \
            al_[fr] = *(const f16x8*)(Abuf + ro_ + ((g * 16) ^ rswz ^ 64));    \
        }                                                                      \
        _Pragma("unroll") for (int fc = 0; fc < 4; fc++) {                     \
            const int ro_ = (wc * 64 + fc * 16 + l15) * 128;                   \
            f16x8 bh_ = *(const f16x8*)(bb_ + ro_ + ((g * 16) ^ rswz));        \
            f16x8 bl_ = *(const f16x8*)(bb_ + ro_ + ((g * 16) ^ rswz ^ 64));   \
            _Pragma("unroll") for (int fr = 0; fr < 4; fr++) {                 \
                acc[fr][fc] = __builtin_amdgcn_mfma_f32_16x16x32_f16(          \
                    ah_[fr], bh_, acc[fr][fc], 0, 0, 0);                       \
                acc[fr][fc] = __builtin_amdgcn_mfma_f32_16x16x32_f16(          \
                    ah_[fr], bl_, acc[fr][fc], 0, 0, 0);                       \
                acc[fr][fc] = __builtin_amdgcn_mfma_f32_16x16x32_f16(          \
                    al_[fr], bh_, acc[fr][fc], 0, 0, 0);                       \
            }                                                                  \
        }                                                                      \
    } while (0)

    LOADA(0);
    cvt_split16(areg, Sh0, Sh1, Sl0, Sl1);
    ISSUE_B(0, 0);
    WRITEA();
    __syncthreads();

#pragma unroll 1
    for (int kt = 0; kt < 32; kt += 2) {
        ISSUE_B(kt + 1, 1);
        LOADA(kt + 1);
        COMPUTE(0);
        cvt_split16(areg, Sh0, Sh1, Sl0, Sl1);
        __syncthreads();
        WRITEA();
        __syncthreads();
        if (kt + 2 < 32) { ISSUE_B(kt + 2, 0); LOADA(kt + 2); }
        COMPUTE(1);
        if (kt + 2 < 32) {
            cvt_split16(areg, Sh0, Sh1, Sl0, Sl1);
            __syncthreads();
            WRITEA();
            __syncthreads();
        }
    }

#undef COMPUTE
#undef WRITEA
#undef LOADA
#undef ISSUE_B

#pragma unroll
    for (int fr = 0; fr < 4; fr++) {
#pragma unroll
        for (int fc = 0; fc < 4; fc++) {
            f32x4 v = acc[fr][fc];
            const int i0 = brow + wr * 64 + fr * 16 + g * 4;
            const int j0 = bcol + wc * 64 + fc * 16;
#pragma unroll
            for (int r = 0; r < 4; r++)
                C0[(size_t)(i0 + r) * 1024 + j0 + l15] = v[r];
        }
    }
}

// ---------------------------------------------------------------------------
// MFMA banded attention (round-18 proven, ~75us): 1024 blocks, 128 q-rows,
// wave owns 32 rows; 37.4 KB LDS; setprio around MFMA clusters.
// ---------------------------------------------------------------------------
__global__ __launch_bounds__(256, 3) void attn_kernel(
        const float* __restrict__ q, const float* __restrict__ k,
        const float* __restrict__ v, const float* __restrict__ s_v,
        const float* __restrict__ s_r, const float* __restrict__ mask_tab,
        float* __restrict__ out) {
    __shared__ unsigned short Kh[32 * 72];
    __shared__ unsigned short Kl[32 * 72];
    __shared__ unsigned short Vh[64 * 40];
    __shared__ unsigned short Vl[64 * 40];
    __shared__ unsigned int   aB[4][32 * 33];
    __shared__ float          msk[256];

    const int bx = blockIdx.x;
    const int h   = bx & 15;
    const int n   = (bx >> 4) & 15;
    const int sub = (bx >> 8) & 1;
    const int b   = bx >> 9;
    const int bh = b * 16 + h;
    const int tid = threadIdx.x;
    const int lane = tid & 63;
    const int wid = tid >> 6;
    const int l15 = lane & 15;
    const int g = lane >> 4;

    msk[tid] = mask_tab[h * 256 + tid];
    const float w = expf(s_v[h]) + 1.0f;
    const float rh = expf(s_r[h]) + 1.0f;

    const int row0 = n * 256 + sub * 128;
    const float* qbase = q + (size_t)bh * 4096 * 64;
    const float* kbase = k + (size_t)bh * 4096 * 64;
    const float* vbase = v + (size_t)bh * 4096 * 64;

    bf16x8 qh[2][2], ql[2][2];
#pragma unroll
    for (int f = 0; f < 2; f++) {
#pragma unroll
        for (int ks = 0; ks < 2; ks++) {
            const float* src = qbase + (size_t)(row0 + wid * 32 + f * 16 + l15) * 64
                               + ks * 32 + g * 8;
            f32x4 x0 = *(const f32x4*)src;
            f32x4 x1 = *(const f32x4*)(src + 4);
            float xs[8] = {x0[0], x0[1], x0[2], x0[3], x1[0], x1[1], x1[2], x1[3]};
            unsigned hb[8], lb[8];
#pragma unroll
            for (int e = 0; e < 8; e++) {
                hb[e] = rn_hi(xs[e]);
                lb[e] = rn_hi(xs[e] - __uint_as_float(hb[e]));
            }
            FragU th, tl;
            th.u = make_uint4((hb[0] >> 16) | hb[1], (hb[2] >> 16) | hb[3],
                              (hb[4] >> 16) | hb[5], (hb[6] >> 16) | hb[7]);
            tl.u = make_uint4((lb[0] >> 16) | lb[1], (lb[2] >> 16) | lb[3],
                              (lb[4] >> 16) | lb[5], (lb[6] >> 16) | lb[7]);
            qh[f][ks] = th.f;
            ql[f][ks] = tl.f;
        }
    }

    int jlo = (int)floorf(256.0f + (float)(sub * 128) - w) + 1;
    if (jlo < 0) jlo = 0;
    if (n == 0 && jlo < 256) jlo = 256;
    jlo &= ~31;
    const int jhi = 256 + sub * 128 + 127;

    const int iw0 = sub * 128 + wid * 32;

    f32x4 acc[2][4];
#pragma unroll
    for (int a = 0; a < 2; a++)
#pragma unroll
        for (int d = 0; d < 4; d++) acc[a][d] = (f32x4)(0.0f);

    const int kj = tid >> 3;
    const int kd = (tid & 7) * 8;
    const int vj = tid & 31;
    const int vd = (tid >> 5) * 8;

    f32x4 kr0, kr1, vr0, vr1;
    {
        const float* ks = kbase + (size_t)((n - 1) * 256 + jlo + kj) * 64 + kd;
        const float* vs = vbase + (size_t)((n - 1) * 256 + jlo + vj) * 64 + vd;
        kr0 = *(const f32x4*)ks;  kr1 = *(const f32x4*)(ks + 4);
        vr0 = *(const f32x4*)vs;  vr1 = *(const f32x4*)(vs + 4);
    }

    for (int jt = jlo; jt <= jhi; jt += 32) {
        __syncthreads();
        {
            float xs[8] = {kr0[0], kr0[1], kr0[2], kr0[3], kr1[0], kr1[1], kr1[2], kr1[3]};
            unsigned hb[8], lb[8];
#pragma unroll
            for (int e = 0; e < 8; e++) {
                hb[e] = rn_hi(xs[e]);
                lb[e] = rn_hi(xs[e] - __uint_as_float(hb[e]));
            }
            *(uint4*)&Kh[kj * 72 + kd] =
                make_uint4((hb[0] >> 16) | hb[1], (hb[2] >> 16) | hb[3],
                           (hb[4] >> 16) | hb[5], (hb[6] >> 16) | hb[7]);
            *(uint4*)&Kl[kj * 72 + kd] =
                make_uint4((lb[0] >> 16) | lb[1], (lb[2] >> 16) | lb[3],
                           (lb[4] >> 16) | lb[5], (lb[6] >> 16) | lb[7]);
        }
        {
            float xs[8] = {vr0[0], vr0[1], vr0[2], vr0[3], vr1[0], vr1[1], vr1[2], vr1[3]};
#pragma unroll
            for (int e = 0; e < 8; e++) {
                unsigned hbv = rn_hi(xs[e]);
                unsigned lbv = rn_hi(xs[e] - __uint_as_float(hbv));
                Vh[(vd + e) * 40 + vj] = (unsigned short)(hbv >> 16);
                Vl[(vd + e) * 40 + vj] = (unsigned short)(lbv >> 16);
            }
        }
        if (jt + 32 <= jhi) {
            const float* ks = kbase + (size_t)((n - 1) * 256 + jt + 32 + kj) * 64 + kd;
            const float* vs = vbase + (size_t)((n - 1) * 256 + jt + 32 + vj) * 64 + vd;
            kr0 = *(const f32x4*)ks;  kr1 = *(const f32x4*)(ks + 4);
            vr0 = *(const f32x4*)vs;  vr1 = *(const f32x4*)(vs + 4);
        }
        __syncthreads();

        const bool live = ((float)(jt + 31) > 256.0f + (float)iw0 - w) &&
                          (jt <= 256 + iw0 + 31);
        if (live) {
            f32x4 sim[2][2];
#pragma unroll
            for (int jf = 0; jf < 2; jf++)
#pragma unroll
                for (int f = 0; f < 2; f++) sim[jf][f] = (f32x4)(0.0f);

            __builtin_amdgcn_s_setprio(1);
#pragma unroll
            for (int jf = 0; jf < 2; jf++) {
#pragma unroll
                for (int ks = 0; ks < 2; ks++) {
                    bf16x8 kah = *(const bf16x8*)&Kh[(jf * 16 + l15) * 72 + ks * 32 + g * 8];
                    bf16x8 kal = *(const bf16x8*)&Kl[(jf * 16 + l15) * 72 + ks * 32 + g * 8];
#pragma unroll
                    for (int f = 0; f < 2; f++) {
                        sim[jf][f] = __builtin_amdgcn_mfma_f32_16x16x32_bf16(
                            kah, qh[f][ks], sim[jf][f], 0, 0, 0);
                        sim[jf][f] = __builtin_amdgcn_mfma_f32_16x16x32_bf16(
                            kah, ql[f][ks], sim[jf][f], 0, 0, 0);
                        sim[jf][f] = __builtin_amdgcn_mfma_f32_16x16x32_bf16(
                            kal, qh[f][ks], sim[jf][f], 0, 0, 0);
                    }
                }
            }
            __builtin_amdgcn_s_setprio(0);

#pragma unroll
            for (int jf = 0; jf < 2; jf++) {
#pragma unroll
                for (int f = 0; f < 2; f++) {
#pragma unroll
                    for (int r = 0; r < 4; r++) {
                        const int jloc = jf * 16 + g * 4 + r;
                        const int iloc = f * 16 + l15;
                        const int relv = (jt + jloc) - 256 - (sub * 128 + wid * 32 + iloc);
                        float m = (relv >= -255 && relv <= 0) ? msk[relv + 255] : 0.0f;
                        float t1 = 1.0f - rh * (1.0f - sim[jf][f][r]);
                        t1 = fmaxf(t1, 0.0f);
                        float alpha = t1 * t1 * m;
                        unsigned ahb = rn_hi(alpha);
                        unsigned alb = rn_hi(alpha - __uint_as_float(ahb));
                        aB[wid][jloc * 33 + iloc] = ahb | (alb >> 16);
                    }
                }
            }

#pragma unroll
            for (int f = 0; f < 2; f++) {
                unsigned a8[8];
#pragma unroll
                for (int e = 0; e < 8; e++)
                    a8[e] = aB[wid][(g * 8 + e) * 33 + f * 16 + l15];
                FragU th, tl;
                th.u = make_uint4((a8[0] >> 16) | (a8[1] & 0xFFFF0000u),
                                  (a8[2] >> 16) | (a8[3] & 0xFFFF0000u),
                                  (a8[4] >> 16) | (a8[5] & 0xFFFF0000u),
                                  (a8[6] >> 16) | (a8[7] & 0xFFFF0000u));
                tl.u = make_uint4((a8[0] << 16 >> 16) | (a8[1] << 16),
                                  (a8[2] << 16 >> 16) | (a8[3] << 16),
                                  (a8[4] << 16 >> 16) | (a8[5] << 16),
                                  (a8[6] << 16 >> 16) | (a8[7] << 16));
                bf16x8 aah = th.f, aal = tl.f;
                __builtin_amdgcn_s_setprio(1);
#pragma unroll
                for (int df = 0; df < 4; df++) {
                    bf16x8 vbh = *(const bf16x8*)&Vh[(df * 16 + l15) * 40 + g * 8];
                    bf16x8 vbl = *(const bf16x8*)&Vl[(df * 16 + l15) * 40 + g * 8];
                    acc[f][df] = __builtin_amdgcn_mfma_f32_16x16x32_bf16(
                        aah, vbh, acc[f][df], 0, 0, 0);
                    acc[f][df] = __builtin_amdgcn_mfma_f32_16x16x32_bf16(
                        aah, vbl, acc[f][df], 0, 0, 0);
                    acc[f][df] = __builtin_amdgcn_mfma_f32_16x16x32_bf16(
                        aal, vbh, acc[f][df], 0, 0, 0);
                }
                __builtin_amdgcn_s_setprio(0);
            }
        }
    }

#pragma unroll
    for (int f = 0; f < 2; f++) {
#pragma unroll
        for (int r = 0; r < 4; r++) {
            float p = 0.0f;
#pragma unroll
            for (int df = 0; df < 4; df++) p = fmaf(acc[f][df][r], acc[f][df][r], p);
            p += __shfl_xor(p, 1);
            p += __shfl_xor(p, 2);
            p += __shfl_xor(p, 4);
            p += __shfl_xor(p, 8);
            float nn = sqrtf(p);
            float sc = tanhf(nn) / (nn + 1e-8f);
            const int trow = row0 + wid * 32 + f * 16 + g * 4 + r;
            float* dst = out + ((size_t)(b * 4096 + trow)) * 1024 + h * 64;
#pragma unroll
            for (int df = 0; df < 4; df++)
                dst[df * 16 + l15] = acc[f][df][r] * sc;
        }
    }
}

// ---------------------------------------------------------------------------
// Workspace layout (peak = 128MB + 16KB, proven):
//   [0,96)MB   : qw/kw/vw; later reused: [0,4)MB = Wo split
//   [96,128)MB : Wq/Wk/Wv split planes (12MB, dead pre-attn) then ao (32MB)
//   [128MB,+16KB) : mask
// ---------------------------------------------------------------------------
extern "C" void kernel_launch(void* const* d_in, const int* in_sizes, int n_in,
                              void* d_out, int out_size, void* d_ws, size_t ws_size,
                              hipStream_t stream) {
    const float* query = (const float*)d_in[0];
    const float* key   = (const float*)d_in[1];
    const float* value = (const float*)d_in[2];
    const float* Wq    = (const float*)d_in[3];
    const float* Wk    = (const float*)d_in[4];
    const float* Wv    = (const float*)d_in[5];
    const float* Wo    = (const float*)d_in[6];
    const float* s_v   = (const float*)d_in[7];
    const float* s_r   = (const float*)d_in[8];
    float* out = (float*)d_out;

    const size_t MB = 1ull << 20;
    char* base = (char*)d_ws;
    float* qw   = (float*)(base);
    float* kw   = (float*)(base + 32 * MB);
    float* vw   = (float*)(base + 64 * MB);
    float* ao   = (float*)(base + 96 * MB);
    char*  w3sp = base + 96 * MB;           // aliases ao (dead before attn)
    char*  wosp = base;                     // aliases qw (written after attn)
    float* mask = (float*)(base + 128 * MB);

    mask_tab_kernel<<<dim3(16), dim3(256), 0, stream>>>(s_v, mask);

    // pre-split Wq/Wk/Wv into the (not-yet-written) ao region
    split_tiles<<<dim3(256, 3), dim3(256), 0, stream>>>(Wq, Wk, Wv, w3sp, 4 * MB);

    // fused QKV projections + l2norm (round-13 proven gemm_ws, 48KB LDS)
    gemm_ws<1><<<dim3(768), dim3(256), 0, stream>>>(
        query, key, value, w3sp, 4 * MB, qw, kw, vw);

    // banded attention (proven version + setprio)
    attn_kernel<<<dim3(1024), dim3(256), 0, stream>>>(
        qw, kw, vw, s_v, s_r, mask, ao);

    // pre-split Wo into the (now-dead) qw region
    split_tiles<<<dim3(256, 1), dim3(256), 0, stream>>>(Wo, Wo, Wo, wosp, 0);

    // output projection (round-15 proven gemm_a2, A = L3-resident ao)
    gemm_a2<0><<<dim3(512), dim3(256), 0, stream>>>(ao, wosp, out);
}